// Round 5
// baseline (167.417 us; speedup 1.0000x reference)
//
#include <hip/hip_runtime.h>

// out[i] = floor(image[i] * 0.5f) — pure elementwise stream, memory-bound.
// image: 8*3*1024*1024 fp32 (25,165,824 elements = 6,291,456 float4s).
// Compulsory traffic: 96 MiB read + 96 MiB write = 192 MiB → ~30 µs @ 6.3 TB/s.
//
// Harness anatomy (decoded rounds 0-4): each timed iteration = two 384 MiB
// poison fills (~119 µs, harness-owned, 6.8 TB/s) + this kernel. Fills
// thrash the 256 MiB LLC.
//
// Load/store-mode matrix at the monolithic shape (kernel µs, measured by
// dur_us subtraction):
//   NT load + NT store      : 47   (R2 best so far; ~4.2 TB/s)
//   cached load + NT store  : 52   (R3 — cached loads LOSE)
//   cached + cached (strided): 64  (R1, confounded shape)
//   NT load + cached store  : THIS ROUND.
// Rationale: the harness fill writes 384 MiB at 6.8 TB/s with plain cached
// stores (full-line write-combining through L2, no RFO — R1's FETCH showed
// no read-for-ownership traffic). NT stores bypass that path and may be the
// whole 4.2-vs-6.3 TB/s gap. Loads stay NT (isolated win in R3).
//
// Kernel shape: monolithic one-float4-per-thread, no loop (best measured).
//
// NOTE: __builtin_nontemporal_* rejects HIP_vector_type structs; use a native
// clang ext_vector_type float4 (identical 16B layout/alignment).

typedef float vfloat4 __attribute__((ext_vector_type(4)));

__global__ __launch_bounds__(256) void stego_halve(const vfloat4* __restrict__ in,
                                                   vfloat4* __restrict__ out,
                                                   int n4) {
    int i = blockIdx.x * 256 + threadIdx.x;
    if (i < n4) {
        vfloat4 v = __builtin_nontemporal_load(&in[i]);  // NT load: R3-isolated win
        vfloat4 r;
        r.x = floorf(v.x * 0.5f);
        r.y = floorf(v.y * 0.5f);
        r.z = floorf(v.z * 0.5f);
        r.w = floorf(v.w * 0.5f);
        out[i] = r;                                      // cached store: L2 write-combine
    }
}

__global__ __launch_bounds__(256) void stego_halve_tail(const float* __restrict__ in,
                                                        float* __restrict__ out,
                                                        int start, int n) {
    int i = start + blockIdx.x * 256 + threadIdx.x;
    if (i < n) {
        out[i] = floorf(in[i] * 0.5f);
    }
}

extern "C" void kernel_launch(void* const* d_in, const int* in_sizes, int n_in,
                              void* d_out, int out_size, void* d_ws, size_t ws_size,
                              hipStream_t stream) {
    const float* image = (const float*)d_in[0];
    float* out = (float*)d_out;
    int n = in_sizes[0];   // 25,165,824

    int n4 = n / 4;        // 6,291,456 float4s
    int tail_start = n4 * 4;

    if (n4 > 0) {
        const int block = 256;
        int grid = (n4 + block - 1) / block;   // 24,576 for the bench shape
        stego_halve<<<grid, block, 0, stream>>>((const vfloat4*)image,
                                                (vfloat4*)out, n4);
    }
    if (tail_start < n) {
        int rem = n - tail_start;
        const int block = 256;
        int grid = (rem + block - 1) / block;
        stego_halve_tail<<<grid, block, 0, stream>>>(image, out, tail_start, n);
    }
}